// Round 1
// baseline (1819.194 us; speedup 1.0000x reference)
//
#include <hip/hip_runtime.h>

#define NUM_FINE 1048576
#define NUM_FEATURES 128
#define NUM_SEG 262144

// Phase 1: histogram of segment ids.
__global__ void count_kernel(const int* __restrict__ ids, int* __restrict__ cnt) {
    int i = blockIdx.x * blockDim.x + threadIdx.x;
    if (i < NUM_FINE) {
        atomicAdd(&cnt[ids[i]], 1);
    }
}

// Phase 2: reciprocal of counts (1/max(c,1)) so the scatter can scale at add time.
__global__ void inv_kernel(const int* __restrict__ cnt, float* __restrict__ inv) {
    int s = blockIdx.x * blockDim.x + threadIdx.x;
    if (s < NUM_SEG) {
        int c = cnt[s];
        inv[s] = 1.0f / (float)(c > 1 ? c : 1);
    }
}

// Phase 3: scatter-add of pre-scaled contributions.
// One thread per (row, 4-feature chunk): float4 coalesced read, 4 fp32 atomics.
__global__ void scatter_kernel(const float* __restrict__ x,
                               const int* __restrict__ ids,
                               const float* __restrict__ inv,
                               float* __restrict__ out) {
    long long t = (long long)blockIdx.x * blockDim.x + threadIdx.x;
    int row = (int)(t >> 5);          // 32 threads per row (128 features / 4)
    int q   = (int)(t & 31);
    int seg = ids[row];               // broadcast within half-wave, L1-hit
    float s = inv[seg];               // 1 MiB table, L2-resident
    const float4 v = *reinterpret_cast<const float4*>(
        x + (long long)row * NUM_FEATURES + (q << 2));
    float* o = out + (long long)seg * NUM_FEATURES + (q << 2);
    atomicAdd(o + 0, v.x * s);
    atomicAdd(o + 1, v.y * s);
    atomicAdd(o + 2, v.z * s);
    atomicAdd(o + 3, v.w * s);
}

extern "C" void kernel_launch(void* const* d_in, const int* in_sizes, int n_in,
                              void* d_out, int out_size, void* d_ws, size_t ws_size,
                              hipStream_t stream) {
    const float* x   = (const float*)d_in[0];
    const int*   ids = (const int*)d_in[1];
    float* out = (float*)d_out;

    int*   cnt = (int*)d_ws;
    float* inv = (float*)((char*)d_ws + (size_t)NUM_SEG * sizeof(int));

    // Zero accumulators every call (harness poisons once, never re-poisons).
    hipMemsetAsync(cnt, 0, (size_t)NUM_SEG * sizeof(int), stream);
    hipMemsetAsync(out, 0, (size_t)NUM_SEG * NUM_FEATURES * sizeof(float), stream);

    count_kernel<<<NUM_FINE / 256, 256, 0, stream>>>(ids, cnt);
    inv_kernel<<<NUM_SEG / 256, 256, 0, stream>>>(cnt, inv);

    long long total = (long long)NUM_FINE * 32;  // threads: rows * 32 chunks
    scatter_kernel<<<(int)(total / 256), 256, 0, stream>>>(x, ids, inv, out);
}

// Round 2
// 365.261 us; speedup vs baseline: 4.9805x; 4.9805x over previous
//
#include <hip/hip_runtime.h>

#define NUM_FINE 1048576
#define NUM_FEATURES 128
#define NUM_SEG 262144

// ---- Phase 1: histogram of segment ids (int atomics, ~4-way contention) ----
__global__ void count_kernel(const int* __restrict__ ids, int* __restrict__ cnt) {
    int i = blockIdx.x * blockDim.x + threadIdx.x;
    atomicAdd(&cnt[ids[i]], 1);
}

// ---- Phase 2a: per-block exclusive scan (1024 elems/block via int4) ----
__global__ void scan1_kernel(const int* __restrict__ cnt, int* __restrict__ base,
                             int* __restrict__ blockSums) {
    __shared__ int lds[256];
    int tid = threadIdx.x;
    int g = blockIdx.x * 1024 + tid * 4;
    int4 a = *reinterpret_cast<const int4*>(cnt + g);
    int s = a.x + a.y + a.z + a.w;
    lds[tid] = s;
    __syncthreads();
    for (int off = 1; off < 256; off <<= 1) {
        int v = (tid >= off) ? lds[tid - off] : 0;
        __syncthreads();
        lds[tid] += v;
        __syncthreads();
    }
    int excl = lds[tid] - s;
    int4 o;
    o.x = excl;
    o.y = o.x + a.x;
    o.z = o.y + a.y;
    o.w = o.z + a.z;
    *reinterpret_cast<int4*>(base + g) = o;
    if (tid == 255) blockSums[blockIdx.x] = lds[255];
}

// ---- Phase 2b: exclusive scan of the 256 block sums (single block) ----
__global__ void scan2_kernel(int* __restrict__ blockSums) {
    __shared__ int lds[256];
    int tid = threadIdx.x;
    int v = blockSums[tid];
    lds[tid] = v;
    __syncthreads();
    for (int off = 1; off < 256; off <<= 1) {
        int t = (tid >= off) ? lds[tid - off] : 0;
        __syncthreads();
        lds[tid] += t;
        __syncthreads();
    }
    blockSums[tid] = lds[tid] - v;  // exclusive
}

// ---- Phase 2c: add block offsets -> final exclusive scan in `base` ----
__global__ void scan3_kernel(int* __restrict__ base, const int* __restrict__ blockSums) {
    int g = blockIdx.x * 1024 + threadIdx.x * 4;
    int add = blockSums[blockIdx.x];
    int4 a = *reinterpret_cast<int4*>(base + g);
    a.x += add; a.y += add; a.z += add; a.w += add;
    *reinterpret_cast<int4*>(base + g) = a;
}

// ---- Phase 3: placement. Mutates base[s] -> segment END offset. ----
__global__ void place_kernel(const int* __restrict__ ids, int* __restrict__ base,
                             int* __restrict__ perm) {
    int i = blockIdx.x * blockDim.x + threadIdx.x;
    int p = atomicAdd(&base[ids[i]], 1);
    perm[p] = i;
}

// ---- Phase 4: gather. One wave (64 lanes) per segment; each lane owns 2 features.
// Each row read is 512 B contiguous (fully coalesced); output written once. ----
__global__ void gather_kernel(const float* __restrict__ x,
                              const int* __restrict__ perm,
                              const int* __restrict__ endArr,  // base after placement
                              const int* __restrict__ cnt,
                              float* __restrict__ out) {
    int wid = (blockIdx.x * blockDim.x + threadIdx.x) >> 6;  // segment id
    int lane = threadIdx.x & 63;
    int end = endArr[wid];
    int c = cnt[wid];
    float2 acc = {0.f, 0.f};
    for (int r = end - c; r < end; ++r) {
        int row = perm[r];
        float2 v = *reinterpret_cast<const float2*>(
            x + (size_t)row * NUM_FEATURES + lane * 2);
        acc.x += v.x;
        acc.y += v.y;
    }
    float inv = 1.0f / (float)(c > 1 ? c : 1);
    float2 o = {acc.x * inv, acc.y * inv};
    *reinterpret_cast<float2*>(out + (size_t)wid * NUM_FEATURES + lane * 2) = o;
}

extern "C" void kernel_launch(void* const* d_in, const int* in_sizes, int n_in,
                              void* d_out, int out_size, void* d_ws, size_t ws_size,
                              hipStream_t stream) {
    const float* x   = (const float*)d_in[0];
    const int*   ids = (const int*)d_in[1];
    float* out = (float*)d_out;

    char* ws = (char*)d_ws;
    int* cnt       = (int*)(ws);                        // 1 MiB
    int* base      = (int*)(ws + (1 << 20));            // 1 MiB
    int* blockSums = (int*)(ws + (2 << 20));            // 1 KiB
    int* perm      = (int*)(ws + (3 << 20));            // 4 MiB

    hipMemsetAsync(cnt, 0, (size_t)NUM_SEG * sizeof(int), stream);

    count_kernel<<<NUM_FINE / 256, 256, 0, stream>>>(ids, cnt);
    scan1_kernel<<<NUM_SEG / 1024, 256, 0, stream>>>(cnt, base, blockSums);
    scan2_kernel<<<1, 256, 0, stream>>>(blockSums);
    scan3_kernel<<<NUM_SEG / 1024, 256, 0, stream>>>(base, blockSums);
    place_kernel<<<NUM_FINE / 256, 256, 0, stream>>>(ids, base, perm);

    // 1 wave per segment, 4 waves per block
    gather_kernel<<<NUM_SEG / 4, 256, 0, stream>>>(x, perm, base, cnt, out);
}

// Round 3
// 285.803 us; speedup vs baseline: 6.3652x; 1.2780x over previous
//
#include <hip/hip_runtime.h>

#define NUM_FINE 1048576
#define NUM_FEATURES 128
#define NUM_SEG 262144

// ---- Phase 1: histogram of segment ids (int atomics), 4 ids/thread ----
__global__ void count_kernel(const int* __restrict__ ids, int* __restrict__ cnt) {
    int i = (blockIdx.x * blockDim.x + threadIdx.x) * 4;
    int4 a = *reinterpret_cast<const int4*>(ids + i);
    atomicAdd(&cnt[a.x], 1);
    atomicAdd(&cnt[a.y], 1);
    atomicAdd(&cnt[a.z], 1);
    atomicAdd(&cnt[a.w], 1);
}

// ---- Phase 2a: per-block exclusive scan (1024 elems/block via int4) ----
__global__ void scan1_kernel(const int* __restrict__ cnt, int* __restrict__ base,
                             int* __restrict__ blockSums) {
    __shared__ int lds[256];
    int tid = threadIdx.x;
    int g = blockIdx.x * 1024 + tid * 4;
    int4 a = *reinterpret_cast<const int4*>(cnt + g);
    int s = a.x + a.y + a.z + a.w;
    lds[tid] = s;
    __syncthreads();
    for (int off = 1; off < 256; off <<= 1) {
        int v = (tid >= off) ? lds[tid - off] : 0;
        __syncthreads();
        lds[tid] += v;
        __syncthreads();
    }
    int excl = lds[tid] - s;
    int4 o;
    o.x = excl;
    o.y = o.x + a.x;
    o.z = o.y + a.y;
    o.w = o.z + a.z;
    *reinterpret_cast<int4*>(base + g) = o;
    if (tid == 255) blockSums[blockIdx.x] = lds[255];
}

// ---- Phase 2b: exclusive scan of the 256 block sums (single block) ----
__global__ void scan2_kernel(int* __restrict__ blockSums) {
    __shared__ int lds[256];
    int tid = threadIdx.x;
    int v = blockSums[tid];
    lds[tid] = v;
    __syncthreads();
    for (int off = 1; off < 256; off <<= 1) {
        int t = (tid >= off) ? lds[tid - off] : 0;
        __syncthreads();
        lds[tid] += t;
        __syncthreads();
    }
    blockSums[tid] = lds[tid] - v;  // exclusive
}

// ---- Phase 2c: add block offsets -> final exclusive scan in `base` ----
__global__ void scan3_kernel(int* __restrict__ base, const int* __restrict__ blockSums) {
    int g = blockIdx.x * 1024 + threadIdx.x * 4;
    int add = blockSums[blockIdx.x];
    int4 a = *reinterpret_cast<int4*>(base + g);
    a.x += add; a.y += add; a.z += add; a.w += add;
    *reinterpret_cast<int4*>(base + g) = a;
}

// ---- Phase 3: placement, 4 ids/thread. Mutates base[s] -> segment END. ----
__global__ void place_kernel(const int* __restrict__ ids, int* __restrict__ base,
                             int* __restrict__ perm) {
    int i = (blockIdx.x * blockDim.x + threadIdx.x) * 4;
    int4 a = *reinterpret_cast<const int4*>(ids + i);
    perm[atomicAdd(&base[a.x], 1)] = i;
    perm[atomicAdd(&base[a.y], 1)] = i + 1;
    perm[atomicAdd(&base[a.z], 1)] = i + 2;
    perm[atomicAdd(&base[a.w], 1)] = i + 3;
}

// ---- Phase 4: gather, one wave per segment, 4 rows in flight (MLP=4). ----
__global__ void gather_kernel(const float* __restrict__ x,
                              const int* __restrict__ perm,
                              const int* __restrict__ endArr,
                              const int* __restrict__ cnt,
                              float* __restrict__ out) {
    int wid = (blockIdx.x * blockDim.x + threadIdx.x) >> 6;  // segment id
    int lane = threadIdx.x & 63;
    int end = endArr[wid];
    int c = cnt[wid];
    float2* op = reinterpret_cast<float2*>(out + (size_t)wid * NUM_FEATURES) + lane;
    if (c == 0) {  // empty segment: mean = 0 (wave-uniform branch)
        *op = make_float2(0.f, 0.f);
        return;
    }
    float2 acc = {0.f, 0.f};
    for (int r = end - c; r < end; r += 4) {
        // wave-uniform clamped batch: 4 perm loads, then 4 independent row loads
        int i0 = perm[r];
        int i1 = perm[(r + 1 < end) ? r + 1 : r];
        int i2 = perm[(r + 2 < end) ? r + 2 : r];
        int i3 = perm[(r + 3 < end) ? r + 3 : r];
        const float2 v0 = *reinterpret_cast<const float2*>(x + (size_t)i0 * NUM_FEATURES + lane * 2);
        const float2 v1 = *reinterpret_cast<const float2*>(x + (size_t)i1 * NUM_FEATURES + lane * 2);
        const float2 v2 = *reinterpret_cast<const float2*>(x + (size_t)i2 * NUM_FEATURES + lane * 2);
        const float2 v3 = *reinterpret_cast<const float2*>(x + (size_t)i3 * NUM_FEATURES + lane * 2);
        float m1 = (r + 1 < end) ? 1.f : 0.f;
        float m2 = (r + 2 < end) ? 1.f : 0.f;
        float m3 = (r + 3 < end) ? 1.f : 0.f;
        acc.x += v0.x + m1 * v1.x + m2 * v2.x + m3 * v3.x;
        acc.y += v0.y + m1 * v1.y + m2 * v2.y + m3 * v3.y;
    }
    float inv = 1.0f / (float)c;
    *op = make_float2(acc.x * inv, acc.y * inv);
}

extern "C" void kernel_launch(void* const* d_in, const int* in_sizes, int n_in,
                              void* d_out, int out_size, void* d_ws, size_t ws_size,
                              hipStream_t stream) {
    const float* x   = (const float*)d_in[0];
    const int*   ids = (const int*)d_in[1];
    float* out = (float*)d_out;

    char* ws = (char*)d_ws;
    int* cnt       = (int*)(ws);                        // 1 MiB
    int* base      = (int*)(ws + (1 << 20));            // 1 MiB
    int* blockSums = (int*)(ws + (2 << 20));            // 1 KiB
    int* perm      = (int*)(ws + (3 << 20));            // 4 MiB

    hipMemsetAsync(cnt, 0, (size_t)NUM_SEG * sizeof(int), stream);

    count_kernel<<<NUM_FINE / 1024, 256, 0, stream>>>(ids, cnt);
    scan1_kernel<<<NUM_SEG / 1024, 256, 0, stream>>>(cnt, base, blockSums);
    scan2_kernel<<<1, 256, 0, stream>>>(blockSums);
    scan3_kernel<<<NUM_SEG / 1024, 256, 0, stream>>>(base, blockSums);
    place_kernel<<<NUM_FINE / 1024, 256, 0, stream>>>(ids, base, perm);

    // 1 wave per segment, 4 waves per block
    gather_kernel<<<NUM_SEG / 4, 256, 0, stream>>>(x, perm, base, cnt, out);
}

// Round 4
// 272.414 us; speedup vs baseline: 6.6781x; 1.0492x over previous
//
#include <hip/hip_runtime.h>

#define NUM_FINE 1048576
#define NUM_FEATURES 128
#define NUM_SEG 262144

// ---- Phase 1: histogram of segment ids (int atomics), 4 ids/thread ----
__global__ void count_kernel(const int* __restrict__ ids, int* __restrict__ cnt) {
    int i = (blockIdx.x * blockDim.x + threadIdx.x) * 4;
    int4 a = *reinterpret_cast<const int4*>(ids + i);
    atomicAdd(&cnt[a.x], 1);
    atomicAdd(&cnt[a.y], 1);
    atomicAdd(&cnt[a.z], 1);
    atomicAdd(&cnt[a.w], 1);
}

// ---- Phase 2a: per-block exclusive scan (1024 elems/block via int4) ----
__global__ void scan1_kernel(const int* __restrict__ cnt, int* __restrict__ base,
                             int* __restrict__ blockSums) {
    __shared__ int lds[256];
    int tid = threadIdx.x;
    int g = blockIdx.x * 1024 + tid * 4;
    int4 a = *reinterpret_cast<const int4*>(cnt + g);
    int s = a.x + a.y + a.z + a.w;
    lds[tid] = s;
    __syncthreads();
    for (int off = 1; off < 256; off <<= 1) {
        int v = (tid >= off) ? lds[tid - off] : 0;
        __syncthreads();
        lds[tid] += v;
        __syncthreads();
    }
    int excl = lds[tid] - s;
    int4 o;
    o.x = excl;
    o.y = o.x + a.x;
    o.z = o.y + a.y;
    o.w = o.z + a.z;
    *reinterpret_cast<int4*>(base + g) = o;
    if (tid == 255) blockSums[blockIdx.x] = lds[255];
}

// ---- Phase 2b (fused): each block re-scans the 256 block sums in LDS,
// picks its own exclusive prefix, and adds it to its 1024 base entries. ----
__global__ void scan3_kernel(int* __restrict__ base, const int* __restrict__ blockSums) {
    __shared__ int lds[256];
    int tid = threadIdx.x;
    int v = blockSums[tid];
    lds[tid] = v;
    __syncthreads();
    for (int off = 1; off < 256; off <<= 1) {
        int t = (tid >= off) ? lds[tid - off] : 0;
        __syncthreads();
        lds[tid] += t;
        __syncthreads();
    }
    int add = (blockIdx.x > 0) ? lds[blockIdx.x - 1] : 0;  // LDS broadcast
    int g = blockIdx.x * 1024 + tid * 4;
    int4 a = *reinterpret_cast<int4*>(base + g);
    a.x += add; a.y += add; a.z += add; a.w += add;
    *reinterpret_cast<int4*>(base + g) = a;
}

// ---- Phase 3: placement, 4 ids/thread. Mutates base[s] -> segment END. ----
__global__ void place_kernel(const int* __restrict__ ids, int* __restrict__ base,
                             int* __restrict__ perm) {
    int i = (blockIdx.x * blockDim.x + threadIdx.x) * 4;
    int4 a = *reinterpret_cast<const int4*>(ids + i);
    perm[atomicAdd(&base[a.x], 1)] = i;
    perm[atomicAdd(&base[a.y], 1)] = i + 1;
    perm[atomicAdd(&base[a.z], 1)] = i + 2;
    perm[atomicAdd(&base[a.w], 1)] = i + 3;
}

// ---- Phase 4: gather. One wave per segment. Each lane holds float4, so
// 32 lanes cover a row and one 64-lane load fetches TWO rows; 4-deep unroll
// puts 8 rows in flight (covers 98% of Poisson(4) segments in one batch). ----
__global__ void gather_kernel(const float* __restrict__ x,
                              const int* __restrict__ perm,
                              const int* __restrict__ endArr,
                              const int* __restrict__ cnt,
                              float* __restrict__ out) {
    int wid = (blockIdx.x << 2) | (threadIdx.x >> 6);  // segment id
    int lane = threadIdx.x & 63;
    int h = lane >> 5;           // which row of the pair this half-wave reads
    int f = (lane & 31) << 2;    // feature offset (float4)
    int end = endArr[wid];
    int c = cnt[wid];
    if (c == 0) {  // empty segment: mean = 0
        if (h == 0)
            *reinterpret_cast<float4*>(out + (size_t)wid * NUM_FEATURES + f) =
                make_float4(0.f, 0.f, 0.f, 0.f);
        return;
    }
    float4 acc = make_float4(0.f, 0.f, 0.f, 0.f);
    for (int r = end - c; r < end; r += 8) {
#pragma unroll
        for (int k = 0; k < 4; ++k) {
            int j = r + (k << 1) + h;
            int jj = (j < end) ? j : (end - 1);   // clamped dup -> L1 hit, free
            int row = perm[jj];
            const float4 v = *reinterpret_cast<const float4*>(
                x + (size_t)row * NUM_FEATURES + f);
            float m = (j < end) ? 1.f : 0.f;
            acc.x += m * v.x;
            acc.y += m * v.y;
            acc.z += m * v.z;
            acc.w += m * v.w;
        }
    }
    // combine even-row (h=0) and odd-row (h=1) partials across the halves
    acc.x += __shfl_xor(acc.x, 32);
    acc.y += __shfl_xor(acc.y, 32);
    acc.z += __shfl_xor(acc.z, 32);
    acc.w += __shfl_xor(acc.w, 32);
    if (h == 0) {
        float inv = 1.0f / (float)c;
        *reinterpret_cast<float4*>(out + (size_t)wid * NUM_FEATURES + f) =
            make_float4(acc.x * inv, acc.y * inv, acc.z * inv, acc.w * inv);
    }
}

extern "C" void kernel_launch(void* const* d_in, const int* in_sizes, int n_in,
                              void* d_out, int out_size, void* d_ws, size_t ws_size,
                              hipStream_t stream) {
    const float* x   = (const float*)d_in[0];
    const int*   ids = (const int*)d_in[1];
    float* out = (float*)d_out;

    char* ws = (char*)d_ws;
    int* cnt       = (int*)(ws);                        // 1 MiB
    int* base      = (int*)(ws + (1 << 20));            // 1 MiB
    int* blockSums = (int*)(ws + (2 << 20));            // 1 KiB
    int* perm      = (int*)(ws + (3 << 20));            // 4 MiB

    hipMemsetAsync(cnt, 0, (size_t)NUM_SEG * sizeof(int), stream);

    count_kernel<<<NUM_FINE / 1024, 256, 0, stream>>>(ids, cnt);
    scan1_kernel<<<NUM_SEG / 1024, 256, 0, stream>>>(cnt, base, blockSums);
    scan3_kernel<<<NUM_SEG / 1024, 256, 0, stream>>>(base, blockSums);
    place_kernel<<<NUM_FINE / 1024, 256, 0, stream>>>(ids, base, perm);

    // 1 wave per segment, 4 waves per block
    gather_kernel<<<NUM_SEG / 4, 256, 0, stream>>>(x, perm, base, cnt, out);
}